// Round 4
// baseline (753.189 us; speedup 1.0000x reference)
//
#include <hip/hip_runtime.h>

typedef unsigned short u16;
typedef unsigned int u32;
typedef __attribute__((ext_vector_type(4))) float f32x4;
typedef __attribute__((ext_vector_type(8))) short short8;  // bf16 bits in i16 lanes

constexpr int TT = 2048;   // tokens = B*S
constexpr int HH = 2048;   // hidden
constexpr int FF = 7168;   // ffn
constexpr int RR = 32;     // lora rank
constexpr int KT = 2;      // top-k
constexpr int NA1 = FF + 256;   // 7424: W1/W3 aug N (A1flat/A3flat appended)
constexpr int NA2 = HH + 256;   // 2304: W2 aug N (A2flat appended)

__device__ __forceinline__ float bf2f(u16 v) {
  union { u32 u; float f; } w; w.u = ((u32)v) << 16; return w.f;
}
__device__ __forceinline__ u16 f2bf(float f) {
  union { float f; u32 u; } w; w.f = f;
  u32 u = w.u;
  return (u16)((u + 0x7FFFu + ((u >> 16) & 1u)) >> 16);
}

// global -> LDS direct DMA, 16 bytes/lane. LDS dest must be linear
// (wave-uniform base + lane*16); swizzle lives in the SOURCE address (rule 21).
__device__ __forceinline__ void gload16(const u16* g, u16* l) {
  __builtin_amdgcn_global_load_lds(
      (__attribute__((address_space(1))) void*)g,
      (__attribute__((address_space(3))) void*)l, 16, 0, 0);
}

// raw barrier (no vmcnt drain) + explicit waits — 8-phase schedule plumbing
__device__ __forceinline__ void bar_mem() { asm volatile("s_barrier" ::: "memory"); }
__device__ __forceinline__ void lgk0() { asm volatile("s_waitcnt lgkmcnt(0)" ::: "memory"); }
template <int N>
__device__ __forceinline__ void vmw() { asm volatile("s_waitcnt vmcnt(%0)" :: "n"(N) : "memory"); }

// ---------------- fused f32 -> bf16 conversion for all 7 weight/act tensors ----------------
// Segment sizes in float4 units.
__global__ __launch_bounds__(256) void prep_kernel(
    const float* __restrict__ X,  u16* __restrict__ Xb,
    const float* __restrict__ W1, const float* __restrict__ A1, u16* __restrict__ W1augb,
    const float* __restrict__ W3, const float* __restrict__ A3, u16* __restrict__ W3augb,
    const float* __restrict__ W2, const float* __restrict__ A2, u16* __restrict__ W2augb) {
  constexpr int n0 = TT * HH / 4;            // X       1,048,576
  constexpr int n1 = FF * HH / 4;            // W1      3,670,016
  constexpr int n2 = 256 * HH / 4;           // A1        131,072
  constexpr int n3 = FF * HH / 4;            // W3
  constexpr int n4 = 256 * HH / 4;           // A3
  constexpr int n5 = HH * FF / 4;            // W2
  constexpr int n6 = 256 * FF / 4;           // A2        458,752
  constexpr int c0 = n0, c1 = c0 + n1, c2 = c1 + n2, c3 = c2 + n3,
                c4 = c3 + n4, c5 = c4 + n5, c6 = c5 + n6;
  int stride = gridDim.x * 256;
  for (int i = blockIdx.x * 256 + threadIdx.x; i < c6; i += stride) {
    const float* src; u16* dst; int j;
    if (i < c0)      { src = X;  dst = Xb;                          j = i; }
    else if (i < c1) { src = W1; dst = W1augb;                      j = i - c0; }
    else if (i < c2) { src = A1; dst = W1augb + (size_t)FF * HH;    j = i - c1; }
    else if (i < c3) { src = W3; dst = W3augb;                      j = i - c2; }
    else if (i < c4) { src = A3; dst = W3augb + (size_t)FF * HH;    j = i - c3; }
    else if (i < c5) { src = W2; dst = W2augb;                      j = i - c4; }
    else             { src = A2; dst = W2augb + (size_t)HH * FF;    j = i - c5; }
    float4 v = ((const float4*)src)[j];
    ushort4 o;
    o.x = f2bf(v.x); o.y = f2bf(v.y); o.z = f2bf(v.z); o.w = f2bf(v.w);
    ((ushort4*)dst)[j] = o;
  }
}

// ---------------- repack B [E, Fdim, R] f32 -> Bm [Fdim, E*R] bf16 ----------------
__global__ __launch_bounds__(256) void repackB_kernel(
    const float* __restrict__ B, u16* __restrict__ Bm, int Fdim) {
  int n = Fdim * 256;
  int stride = gridDim.x * 256;
  for (int i = blockIdx.x * 256 + threadIdx.x; i < n; i += stride) {
    int f = i >> 8, c = i & 255, e = c >> 5, r = c & 31;
    Bm[i] = f2bf(B[((size_t)e * Fdim + f) * RR + r]);
  }
}

// ---------------- gating: logits -> top2 -> weights (f32 exact) ----------------
__global__ __launch_bounds__(64) void gating_kernel(
    const float* __restrict__ X, const float* __restrict__ Wg,
    int* __restrict__ sel, float* __restrict__ rw) {
  int t = blockIdx.x;
  int lane = threadIdx.x;
  const float* x = X + (size_t)t * HH;
  float acc[8] = {};
  for (int h = lane; h < HH; h += 64) {
    float xv = x[h];
#pragma unroll
    for (int e = 0; e < 8; e++) acc[e] += xv * Wg[e * HH + h];
  }
#pragma unroll
  for (int e = 0; e < 8; e++)
    for (int off = 32; off; off >>= 1) acc[e] += __shfl_down(acc[e], off);
  if (lane == 0) {
    int b0 = 0; float l0 = acc[0];
    for (int e = 1; e < 8; e++) if (acc[e] > l0) { l0 = acc[e]; b0 = e; }
    int b1 = -1; float l1 = 0.f;
    for (int e = 0; e < 8; e++) {
      if (e == b0) continue;
      if (b1 < 0 || acc[e] > l1) { l1 = acc[e]; b1 = e; }
    }
    float p = 1.f / (1.f + __expf(l1 - l0));
    sel[t * 2 + 0] = b0; sel[t * 2 + 1] = b1;
    rw[t * 2 + 0] = p;   rw[t * 2 + 1] = 1.f - p;
  }
}

// ================= 256x256 8-phase MFMA GEMM (T1+T2+T3+T4+T5) =================
// At the ~5.5 TB/s aggregate staging roofline (R3 analysis) — do not touch.
__device__ __forceinline__ void stageH(const u16* g, int stride, int row0, int k0,
                                       u16* l) {
  const int tid = threadIdx.x;
#pragma unroll
  for (int j = 0; j < 2; ++j) {
    int c = (j << 9) + tid;            // 0..1023 -> 128 rows x 64 cols
    int row = c >> 3, c8 = c & 7;
    int sc = ((c8 ^ (row & 7)) << 3);  // pre-swizzled source column
    gload16(g + (size_t)(row0 + row) * stride + (k0 + sc), l + c * 8);
  }
}

#define RD_A(buf, mo)                                                         \
  _Pragma("unroll") for (int j = 0; j < 4; ++j)                               \
  _Pragma("unroll") for (int ks = 0; ks < 2; ++ks) {                          \
    int row = wmw + (mo + j) * 16 + r15;                                      \
    a[j * 2 + ks] = *(const short8*)((buf) + row * 64 +                       \
                                     (((ks * 4 + q) ^ (row & 7)) << 3));      \
  }
#define RD_B(buf, reg, no)                                                    \
  _Pragma("unroll") for (int n = 0; n < 2; ++n)                               \
  _Pragma("unroll") for (int ks = 0; ks < 2; ++ks) {                          \
    int row = wnw + (no + n) * 16 + r15;                                      \
    reg[n * 2 + ks] = *(const short8*)((buf) + row * 64 +                     \
                                       (((ks * 4 + q) ^ (row & 7)) << 3));    \
  }
#define MMQ(mo, reg, no)                                                      \
  _Pragma("unroll") for (int m = 0; m < 4; ++m)                               \
  _Pragma("unroll") for (int n = 0; n < 2; ++n)                               \
  _Pragma("unroll") for (int ks = 0; ks < 2; ++ks)                            \
    acc[mo + m][no + n] = __builtin_amdgcn_mfma_f32_16x16x32_bf16(            \
        a[m * 2 + ks], reg[n * 2 + ks], acc[mo + m][no + n], 0, 0, 0);

__global__ __launch_bounds__(512, 2) void gemm256(
    const u16* A0, const u16* A1p, const u16* B0, const u16* B1p,
    u16* Cb0, u16* Cb1, int N, int Kd) {
  const u16* A  = blockIdx.z ? A1p : A0;
  const u16* Bm = blockIdx.z ? B1p : B0;
  u16* Cb       = blockIdx.z ? Cb1 : Cb0;

  __shared__ __align__(16) u16 S[81920];  // 160 KiB: A x3 | B x2 (256x64 each)
  u16* Acur  = S;
  u16* Anext = S + 16384;
  u16* Afree = S + 32768;
  u16* B0b   = S + 49152;
  u16* B1b   = S + 65536;

  // XCD-aware bijective swizzle (nwg % 8 == 0 for both call sites), N-chunked.
  const int gx = gridDim.x, gy = gridDim.y;
  const int nwg = gx * gy;
  const int orig = blockIdx.y * gx + blockIdx.x;
  const int wg = (orig & 7) * (nwg >> 3) + (orig >> 3);
  const int tn = (wg / gy) * 256;
  const int tm = (wg % gy) * 256;

  const int tid = threadIdx.x;
  const int lane = tid & 63, wave = tid >> 6;
  const int wmw = (wave >> 2) * 128;   // wave M offset (2 groups)
  const int wnw = (wave & 3) * 64;     // wave N offset (4 groups)
  const int r15 = lane & 15, q = lane >> 4;

  f32x4 acc[8][4] = {};
  short8 a[8], bl[4], bh[4];

  const int nIter = Kd >> 7;   // pairs of 64-wide K-tiles

  // prologue: t0 (A+B) then t1 (A+B); oldest 8 = t0 -> vmw<8> drains exactly t0
  stageH(A,  Kd, tm,       0,  Acur);
  stageH(A,  Kd, tm + 128, 0,  Acur + 8192);
  stageH(Bm, Kd, tn,       0,  B0b);
  stageH(Bm, Kd, tn + 128, 0,  B0b + 8192);
  stageH(A,  Kd, tm,       64, Anext);
  stageH(A,  Kd, tm + 128, 64, Anext + 8192);
  stageH(Bm, Kd, tn,       64, B1b);
  stageH(Bm, Kd, tn + 128, 64, B1b + 8192);
  vmw<8>();
  bar_mem();

  for (int it = 0; it < nIter; ++it) {
    const bool st = (it + 1 < nIter);
    const int k2 = (2 * it + 2) << 6;
    const int k3 = (2 * it + 3) << 6;

    // ---- K-tile t0 (Acur, B0b) ----
    RD_A(Acur, 0) RD_B(B0b, bl, 0)
    if (st) stageH(A, Kd, tm, k2, Afree);
    bar_mem(); lgk0();
    __builtin_amdgcn_s_setprio(1); MMQ(0, bl, 0) __builtin_amdgcn_s_setprio(0);
    bar_mem();
    RD_B(B0b, bh, 2)
    if (st) stageH(A, Kd, tm + 128, k2, Afree + 8192);
    bar_mem(); lgk0();
    __builtin_amdgcn_s_setprio(1); MMQ(0, bh, 2) __builtin_amdgcn_s_setprio(0);
    bar_mem();
    RD_A(Acur, 4)
    if (st) stageH(Bm, Kd, tn, k2, B0b);
    bar_mem(); lgk0();
    __builtin_amdgcn_s_setprio(1); MMQ(4, bh, 2) __builtin_amdgcn_s_setprio(0);
    bar_mem();
    if (st) stageH(Bm, Kd, tn + 128, k2, B0b + 8192);
    bar_mem();
    __builtin_amdgcn_s_setprio(1); MMQ(4, bl, 0) __builtin_amdgcn_s_setprio(0);
    if (st) vmw<8>(); else vmw<0>();
    bar_mem();

    // ---- K-tile t1 (Anext, B1b) ----
    RD_A(Anext, 0) RD_B(B1b, bl, 0)
    if (st) stageH(A, Kd, tm, k3, Acur);
    bar_mem(); lgk0();
    __builtin_amdgcn_s_setprio(1); MMQ(0, bl, 0) __builtin_amdgcn_s_setprio(0);
    bar_mem();
    RD_B(B1b, bh, 2)
    if (st) stageH(A, Kd, tm + 128, k3, Acur + 8192);
    bar_mem(); lgk0();
    __builtin_amdgcn_s_setprio(1); MMQ(0, bh, 2) __builtin_amdgcn_s_setprio(0);
    bar_mem();
    RD_A(Anext, 4)
    if (st) stageH(Bm, Kd, tn, k3, B1b);
    bar_mem(); lgk0();
    __builtin_amdgcn_s_setprio(1); MMQ(4, bh, 2) __builtin_amdgcn_s_setprio(0);
    bar_mem();
    if (st) stageH(Bm, Kd, tn + 128, k3, B1b + 8192);
    bar_mem();
    __builtin_amdgcn_s_setprio(1); MMQ(4, bl, 0) __builtin_amdgcn_s_setprio(0);
    if (st) vmw<8>();
    bar_mem();

    u16* tmp = Afree; Afree = Anext; Anext = Acur; Acur = tmp;
  }

#pragma unroll
  for (int m = 0; m < 8; ++m)
#pragma unroll
    for (int n = 0; n < 4; ++n)
#pragma unroll
      for (int i = 0; i < 4; ++i) {
        int r = tm + wmw + m * 16 + q * 4 + i;
        int cc = tn + wnw + n * 16 + r15;
        Cb[(size_t)r * N + cc] = f2bf(acc[m][n][i]);
      }
}

// ---------------- 128x128 MFMA GEMM (kept for lora2: K=256, f32 out) ----------------
__global__ __launch_bounds__(256) void gemm_bt(
    const u16* A0, const u16* A1p,
    const u16* B0, const u16* B1p,
    u16* Cb0, u16* Cb1, float* Cf0, float* Cf1,
    int N, int Kd, int out_bf16) {
  const u16* A  = blockIdx.z ? A1p : A0;
  const u16* Bm = blockIdx.z ? B1p : B0;
  u16* Cb       = blockIdx.z ? Cb1 : Cb0;
  float* Cf     = blockIdx.z ? Cf1 : Cf0;

  __shared__ __align__(16) u16 As[128 * 64];
  __shared__ __align__(16) u16 Bs[128 * 64];

  int tid = threadIdx.x;
  int tn = blockIdx.x * 128;
  int tm = blockIdx.y * 128;
  int lane = tid & 63;
  int wave = tid >> 6;
  int wm = (wave >> 1) * 64, wn = (wave & 1) * 64;
  const int r15 = lane & 15, q = lane >> 4;

  f32x4 acc[4][4] = {};

  for (int k0 = 0; k0 < Kd; k0 += 64) {
#pragma unroll
    for (int it = 0; it < 4; it++) {
      int c = it * 256 + tid;
      int row = c >> 3, c8 = c & 7;
      int scol = ((c8 ^ (row & 7)) << 3);
      gload16(A + (size_t)(tm + row) * Kd + (k0 + scol), As + c * 8);
      gload16(Bm + (size_t)(tn + row) * Kd + (k0 + scol), Bs + c * 8);
    }
    __syncthreads();
#pragma unroll
    for (int kk = 0; kk < 2; kk++) {
      short8 af[4], bfr[4];
#pragma unroll
      for (int mi = 0; mi < 4; mi++) {
        int row = wm + mi * 16 + r15;
        int kc = (kk * 4 + q) ^ (row & 7);
        af[mi] = *(const short8*)(As + row * 64 + kc * 8);
      }
#pragma unroll
      for (int ni = 0; ni < 4; ni++) {
        int row = wn + ni * 16 + r15;
        int kc = (kk * 4 + q) ^ (row & 7);
        bfr[ni] = *(const short8*)(Bs + row * 64 + kc * 8);
      }
#pragma unroll
      for (int mi = 0; mi < 4; mi++)
#pragma unroll
        for (int ni = 0; ni < 4; ni++)
          acc[mi][ni] = __builtin_amdgcn_mfma_f32_16x16x32_bf16(af[mi], bfr[ni], acc[mi][ni], 0, 0, 0);
    }
    __syncthreads();
  }
#pragma unroll
  for (int mi = 0; mi < 4; mi++)
#pragma unroll
    for (int ni = 0; ni < 4; ni++)
#pragma unroll
      for (int i = 0; i < 4; i++) {
        int r = tm + wm + mi * 16 + q * 4 + i;
        int cc = tn + wn + ni * 16 + r15;
        float v = acc[mi][ni][i];
        if (out_bf16) Cb[(size_t)r * N + cc] = f2bf(v);
        else          Cf[(size_t)r * N + cc] = v;
      }
}

// ---------------- mask/expand: a1_all/a3_all (Y-aug cols) -> zero-padded ahat ----------------
__global__ __launch_bounds__(256) void mask13_kernel(
    const u16* __restrict__ Y1, const u16* __restrict__ Y3,
    const int* __restrict__ sel, u16* __restrict__ ah1, u16* __restrict__ ah3) {
  int tk = blockIdx.x;
  int t = tk >> 1;
  int e = sel[tk] & 7;
  int c = threadIdx.x;
  bool in = (c >> 5) == e;
  ah1[(size_t)tk * 256 + c] = in ? Y1[(size_t)t * NA1 + FF + c] : (u16)0;
  ah3[(size_t)tk * 256 + c] = in ? Y3[(size_t)t * NA1 + FF + c] : (u16)0;
}

__global__ __launch_bounds__(256) void mask2_kernel(
    const u16* __restrict__ down_aug, const int* __restrict__ sel,
    u16* __restrict__ ah2) {
  int tk = blockIdx.x;
  int t = tk >> 1, k = tk & 1;
  int e = sel[tk] & 7;
  int c = threadIdx.x;
  ah2[(size_t)tk * 256 + c] =
      ((c >> 5) == e) ? down_aug[((size_t)k * TT + t) * NA2 + HH + c] : (u16)0;
}

// ---------------- fused lora1/lora3 GEMM + add-base + silu -> X2 (B-resident) ----------------
// Per block: f-tile 128, both Bm1/Bm3 panels fully resident in LDS (128 KiB,
// staged ONCE), then loop 4 tk-tiles of 128 — cuts B re-staging 4x vs old
// per-tk-block staging. 8 waves: 2 tk-sub (64) x 4 f-sub (32). No barriers in
// the tk loop (B is static).
__global__ __launch_bounds__(512) void lora_silu2(
    const u16* __restrict__ ah1, const u16* __restrict__ ah3,
    const u16* __restrict__ Bm1, const u16* __restrict__ Bm3,
    const u16* __restrict__ Y1, const u16* __restrict__ Y3,
    u16* __restrict__ X2) {
  __shared__ __align__(16) u16 Bs[2][4][128 * 64];  // [mat][kchunk][swizzled 128x64]
  const int tid = threadIdx.x;
  const int tn = blockIdx.x * 128;        // f tile
  const int lane = tid & 63, wave = tid >> 6;
  const int wm = (wave >> 2) * 64;        // tk-sub offset
  const int wn = (wave & 3) * 32;         // f-sub offset
  const int r15 = lane & 15, q = lane >> 4;

  // stage both B panels (K=256 as 4 chunks of 64), linear dest + pre-swizzled src
  for (int c = 0; c < 4; ++c) {
#pragma unroll
    for (int j = 0; j < 2; ++j) {
      int idx = (j << 9) + tid;           // 0..1023 -> 128 rows x 8 col-groups
      int row = idx >> 3, c8 = idx & 7;
      int sc = ((c8 ^ (row & 7)) << 3);
      gload16(Bm1 + (size_t)(tn + row) * 256 + (c * 64 + sc), &Bs[0][c][idx * 8]);
      gload16(Bm3 + (size_t)(tn + row) * 256 + (c * 64 + sc), &Bs[1][c][idx * 8]);
    }
  }
  vmw<0>();
  __syncthreads();

  for (int t = 0; t < 4; ++t) {
    const int tm = (blockIdx.y * 4 + t) * 128;   // tk slot tile
    f32x4 acc1[4][2] = {}, acc3[4][2] = {};
    for (int c = 0; c < 4; ++c) {
#pragma unroll
      for (int kk = 0; kk < 2; ++kk) {
        short8 a1f[4], a3f[4], b1f[2], b3f[2];
#pragma unroll
        for (int mi = 0; mi < 4; ++mi) {
          int row = tm + wm + mi * 16 + r15;
          size_t o = (size_t)row * 256 + c * 64 + (kk * 4 + q) * 8;
          a1f[mi] = *(const short8*)(ah1 + o);
          a3f[mi] = *(const short8*)(ah3 + o);
        }
#pragma unroll
        for (int ni = 0; ni < 2; ++ni) {
          int row = wn + ni * 16 + r15;
          int kc = (kk * 4 + q) ^ (row & 7);
          b1f[ni] = *(const short8*)(&Bs[0][c][row * 64 + kc * 8]);
          b3f[ni] = *(const short8*)(&Bs[1][c][row * 64 + kc * 8]);
        }
#pragma unroll
        for (int mi = 0; mi < 4; ++mi)
#pragma unroll
          for (int ni = 0; ni < 2; ++ni) {
            acc1[mi][ni] = __builtin_amdgcn_mfma_f32_16x16x32_bf16(a1f[mi], b1f[ni], acc1[mi][ni], 0, 0, 0);
            acc3[mi][ni] = __builtin_amdgcn_mfma_f32_16x16x32_bf16(a3f[mi], b3f[ni], acc3[mi][ni], 0, 0, 0);
          }
      }
    }
#pragma unroll
    for (int mi = 0; mi < 4; ++mi)
#pragma unroll
      for (int ni = 0; ni < 2; ++ni)
#pragma unroll
        for (int i = 0; i < 4; ++i) {
          int row = tm + wm + mi * 16 + q * 4 + i;   // tk slot
          int f = tn + wn + ni * 16 + r15;
          int t2 = row >> 1, k = row & 1;
          float x1 = bf2f(Y1[(size_t)t2 * NA1 + f]) + acc1[mi][ni][i];
          float x3 = bf2f(Y3[(size_t)t2 * NA1 + f]) + acc3[mi][ni][i];
          float sig = 1.f / (1.f + __expf(-x1));
          X2[((size_t)k * TT + t2) * FF + f] = f2bf(x1 * sig * x3);
        }
  }
}

// ---------------- out = sum_k rw_k * (down_k + lora2_k)  (f32 out, vectorized) ----------------
__global__ __launch_bounds__(256) void final_kernel(
    const u16* __restrict__ down_aug, const float* __restrict__ L2b,
    const float* __restrict__ rw, float* __restrict__ out) {
  int t = blockIdx.x;
  float r0 = rw[t * 2], r1 = rw[t * 2 + 1];
  int h = threadIdx.x * 8;   // 256 threads * 8 = 2048 = HH exactly
  short8 d0v = *(const short8*)(down_aug + (size_t)t * NA2 + h);
  short8 d1v = *(const short8*)(down_aug + ((size_t)TT + t) * NA2 + h);
  const float* l0p = L2b + (size_t)(t * 2) * HH + h;
  const float* l1p = L2b + (size_t)(t * 2 + 1) * HH + h;
  f32x4 l0a = *(const f32x4*)(l0p),     l0b = *(const f32x4*)(l0p + 4);
  f32x4 l1a = *(const f32x4*)(l1p),     l1b = *(const f32x4*)(l1p + 4);
  f32x4 oa, ob;
#pragma unroll
  for (int j = 0; j < 4; j++) {
    oa[j] = r0 * (bf2f((u16)d0v[j])     + l0a[j]) + r1 * (bf2f((u16)d1v[j])     + l1a[j]);
    ob[j] = r0 * (bf2f((u16)d0v[j + 4]) + l0b[j]) + r1 * (bf2f((u16)d1v[j + 4]) + l1b[j]);
  }
  float* op = out + (size_t)t * HH + h;
  *(f32x4*)(op)     = oa;
  *(f32x4*)(op + 4) = ob;
}

extern "C" void kernel_launch(void* const* d_in, const int* in_sizes, int n_in,
                              void* d_out, int out_size, void* d_ws, size_t ws_size,
                              hipStream_t stream) {
  if (n_in < 11) return;
  const float* X  = (const float*)d_in[0];
  const float* Wg = (const float*)d_in[1];
  const float* W1 = (const float*)d_in[2];
  const float* W2 = (const float*)d_in[3];
  const float* W3 = (const float*)d_in[4];
  const float* A1 = (const float*)d_in[5];
  const float* B1 = (const float*)d_in[6];
  const float* A2 = (const float*)d_in[7];
  const float* B2 = (const float*)d_in[8];
  const float* A3 = (const float*)d_in[9];
  const float* B3 = (const float*)d_in[10];
  float* out = (float*)d_out;

  char* ws = (char*)d_ws;
  size_t off = 0;
  auto take = [&](size_t bytes) -> void* {
    void* p = ws + off;
    off += (bytes + 255) & ~(size_t)255;
    return p;
  };
  u16*   Xb     = (u16*)take((size_t)TT * HH * 2);
  u16*   W1augb = (u16*)take((size_t)NA1 * HH * 2);   // rows: W1 | A1flat
  u16*   W3augb = (u16*)take((size_t)NA1 * HH * 2);   // rows: W3 | A3flat
  u16*   W2augb = (u16*)take((size_t)NA2 * FF * 2);   // rows: W2 | A2flat
  u16*   Bm1    = (u16*)take((size_t)FF * 256 * 2);
  u16*   Bm3    = (u16*)take((size_t)FF * 256 * 2);
  u16*   Bm2    = (u16*)take((size_t)HH * 256 * 2);
  u16*   Y1aug  = (u16*)take((size_t)TT * NA1 * 2);
  u16*   Y3aug  = (u16*)take((size_t)TT * NA1 * 2);
  u16*   ah1    = (u16*)take((size_t)TT * KT * 256 * 2);
  u16*   ah3    = (u16*)take((size_t)TT * KT * 256 * 2);
  u16*   ah2    = (u16*)take((size_t)TT * KT * 256 * 2);
  u16*   X2     = (u16*)take((size_t)KT * TT * FF * 2);
  int*   sel    = (int*)take((size_t)TT * KT * 4);
  float* rw     = (float*)take((size_t)TT * KT * 4);
  if (off > ws_size) return;
  // Aliases into regions that are dead by the time these are written:
  // down_aug (2*2048*2304*2 = 18.9 MB) overlays W1augb (dead after GEMM13).
  // L2b (4096*2048*4 = 33.6 MB) overlays W3augb + start of W2augb (both dead after down GEMM).
  u16*   down_aug = W1augb;
  float* L2b      = (float*)W3augb;

  // --- precompute: fused bf16 casts + repacks + gating ---
  prep_kernel<<<2048, 256, 0, stream>>>(X, Xb, W1, A1, W1augb, W3, A3, W3augb,
                                        W2, A2, W2augb);
  repackB_kernel<<<1024, 256, 0, stream>>>(B1, Bm1, FF);
  repackB_kernel<<<1024, 256, 0, stream>>>(B3, Bm3, FF);
  repackB_kernel<<<1024, 256, 0, stream>>>(B2, Bm2, HH);
  gating_kernel<<<TT, 64, 0, stream>>>(X, Wg, sel, rw);

  // --- Y1aug/Y3aug = Xb @ [W1|A1flat]^T, [W3|A3flat]^T  (256² 8-phase) ---
  gemm256<<<dim3(NA1 / 256, TT / 256, 2), 512, 0, stream>>>(
      Xb, Xb, W1augb, W3augb, Y1aug, Y3aug, NA1, HH);
  mask13_kernel<<<TT * KT, 256, 0, stream>>>(Y1aug, Y3aug, sel, ah1, ah3);
  // --- X2 = silu(Y1 + ah1@Bm1^T) * (Y3 + ah3@Bm3^T)  (B-resident, tk-quad) ---
  lora_silu2<<<dim3(FF / 128, TT * KT / 128 / 4), 512, 0, stream>>>(
      ah1, ah3, Bm1, Bm3, Y1aug, Y3aug, X2);
  // --- down_aug = X2[k] @ [W2|A2flat]^T  (256² 8-phase) ---
  gemm256<<<dim3(NA2 / 256, TT / 256, 2), 512, 0, stream>>>(
      X2, X2 + (size_t)TT * FF, W2augb, W2augb,
      down_aug, down_aug + (size_t)TT * NA2, NA2, FF);
  mask2_kernel<<<TT * KT, 256, 0, stream>>>(down_aug, sel, ah2);
  // --- L2b = ah2 @ Bm2^T ---
  gemm_bt<<<dim3(HH / 128, TT * KT / 128, 1), 256, 0, stream>>>(
      ah2, ah2, Bm2, Bm2, nullptr, nullptr, L2b, L2b, HH, 256, 0);
  final_kernel<<<TT, 256, 0, stream>>>(down_aug, L2b, rw, out);
}